// Round 5
// baseline (466.570 us; speedup 1.0000x reference)
//
#include <hip/hip_runtime.h>

#define DIM 256
#define NC 12

typedef __attribute__((ext_vector_type(8))) short short8;
typedef __attribute__((ext_vector_type(4))) float f32x4;

__device__ __forceinline__ short f32bf(float f) {
    unsigned u = __builtin_bit_cast(unsigned, f);
    unsigned r = u + 0x7FFFu + ((u >> 16) & 1u);
    return (short)(r >> 16);
}

template<int CTRL>
__device__ __forceinline__ unsigned dppmax(unsigned x) {
    unsigned y = (unsigned)__builtin_amdgcn_update_dpp(0, (int)x, CTRL, 0xF, 0xF, true);
    return x > y ? x : y;
}

// ---------------------------------------------------------------- prep ------
__global__ __launch_bounds__(256) void k_prep(const float* __restrict__ bank,
        const float* __restrict__ W1, const float* __restrict__ W2,
        short* __restrict__ bnbf, double* __restrict__ binv,
        short* __restrict__ w1bf, short* __restrict__ w2bf)
{
    __shared__ double part[4];
    __shared__ double s_inv;
    const int bid = blockIdx.x, t = threadIdx.x;
    if (bid < 1024) {
        const int row = bid;
        if (row < 1000) {
            float v = bank[(size_t)row * DIM + t];
            double ssq = (double)v * (double)v;
            for (int o = 32; o > 0; o >>= 1) ssq += __shfl_down(ssq, o);
            if ((t & 63) == 0) part[t >> 6] = ssq;
            __syncthreads();
            if (t == 0) {
                double s = part[0] + part[1] + part[2] + part[3];
                double n = sqrt(s); if (n < 1e-12) n = 1e-12;
                double inv = 1.0 / n;
                binv[row] = inv; s_inv = inv;
            }
            __syncthreads();
            bnbf[(size_t)row * DIM + t] = f32bf((float)((double)v * s_inv));
        } else {
            bnbf[(size_t)row * DIM + t] = 0;
            if (t == 0) binv[row] = 0.0;
        }
    } else if (bid < 1536) {
        const int i = (bid - 1024) * 256 + t;
        w1bf[i] = f32bf(W1[i]);
    } else {
        const int i = (bid - 1536) * 256 + t;
        w2bf[i] = f32bf(W2[i]);
    }
}

// ------------------------------------------------- sims + select (v3) -------
// v2 was occupancy-starved: 66 KB LDS -> 2 blocks/CU x 4 waves = 8 waves/CU
// (22%), so the serial-dependency select chains and L2-latency A-loads had
// nothing to hide under. v3 keeps the same 66 KB S-tile but uses 512-thread
// blocks (8 waves): 2 blocks/CU now = 16 waves/CU (4/SIMD, 116 VGPR x 4 =
// 464 fits the 512-reg SIMD file). Each wave owns 16 of 128 bank rows per
// chunk (8 chunks); select splits 4 queries/wave. Identical MFMA inputs and
// select logic -> bit-identical output.
__global__ __launch_bounds__(512) void k_sims(const float* __restrict__ feat,
        const short* __restrict__ bnbf, int* __restrict__ top)
{
    __shared__ alignas(16) short S[32 * 1032];
    const int t = threadIdx.x, lane = t & 63, w = t >> 6;   // w = 0..7
    const int n16 = lane & 15, q4 = lane >> 4;
    const int qb = blockIdx.x * 32;

    // Q fragments: lane reads feat[qb + nt*16 + n16][kc*32 + q4*8 .. +8]
    short8 bq[8][2];
    #pragma unroll
    for (int kc = 0; kc < 8; ++kc)
        #pragma unroll
        for (int nt = 0; nt < 2; ++nt) {
            const float4* s = (const float4*)(feat + (size_t)(qb + nt * 16 + n16) * DIM + kc * 32 + q4 * 8);
            float4 v0 = s[0], v1 = s[1];
            short8 f;
            f[0] = f32bf(v0.x); f[1] = f32bf(v0.y); f[2] = f32bf(v0.z); f[3] = f32bf(v0.w);
            f[4] = f32bf(v1.x); f[5] = f32bf(v1.y); f[6] = f32bf(v1.z); f[7] = f32bf(v1.w);
            bq[kc][nt] = f;
        }

    // A base: bank row (w*16 + n16), column q4*8; chunk = 128 rows = 65536 B
    const char* Abase = (const char*)bnbf + ((size_t)(w * 16 + n16) * DIM + q4 * 8) * 2;
    const f32x4 vzero = {0.f, 0.f, 0.f, 0.f};

    short8 af[8], nx[8];
    #pragma unroll
    for (int kc = 0; kc < 8; ++kc)
        af[kc] = *(const short8*)(Abase + kc * 64);

    #pragma unroll 2
    for (int chunk = 0; chunk < 8; ++chunk) {
        if (chunk < 7) {
            const char* nb = Abase + (size_t)(chunk + 1) * 65536;
            #pragma unroll
            for (int kc = 0; kc < 8; ++kc)
                nx[kc] = *(const short8*)(nb + kc * 64);
        }
        f32x4 acc0 = vzero, acc1 = vzero;
        #pragma unroll
        for (int kc = 0; kc < 8; ++kc) {
            acc0 = __builtin_amdgcn_mfma_f32_16x16x32_bf16(af[kc], bq[kc][0], acc0, 0, 0, 0);
            acc1 = __builtin_amdgcn_mfma_f32_16x16x32_bf16(af[kc], bq[kc][1], acc1, 0, 0, 0);
        }
        const int bankb = chunk * 128 + w * 16 + q4 * 4;
        {
            uint2 u;
            u.x = ((unsigned)(unsigned short)f32bf(acc0[0])) |
                  (((unsigned)(unsigned short)f32bf(acc0[1])) << 16);
            u.y = ((unsigned)(unsigned short)f32bf(acc0[2])) |
                  (((unsigned)(unsigned short)f32bf(acc0[3])) << 16);
            *(uint2*)(S + (size_t)n16 * 1032 + bankb) = u;
            u.x = ((unsigned)(unsigned short)f32bf(acc1[0])) |
                  (((unsigned)(unsigned short)f32bf(acc1[1])) << 16);
            u.y = ((unsigned)(unsigned short)f32bf(acc1[2])) |
                  (((unsigned)(unsigned short)f32bf(acc1[3])) << 16);
            *(uint2*)(S + (size_t)(16 + n16) * 1032 + bankb) = u;
        }
        #pragma unroll
        for (int kc = 0; kc < 8; ++kc) af[kc] = nx[kc];
    }
    __syncthreads();

    // ---- fused select: 8 waves x 4 queries each, reads from LDS ----
    for (int i = 0; i < 4; ++i) {
        const int ql = w * 4 + i;
        const uint4* p = (const uint4*)(S + (size_t)ql * 1032 + lane * 16);
        uint4 a = p[0], b = p[1];

        unsigned k[16];
        {
            unsigned words[8] = {a.x, a.y, a.z, a.w, b.x, b.y, b.z, b.w};
            #pragma unroll
            for (int j = 0; j < 16; ++j) {
                unsigned h = (j & 1) ? (words[j >> 1] >> 16) : (words[j >> 1] & 0xFFFFu);
                unsigned m = (h ^ 0x8000u) ^ ((0u - (h >> 15)) & 0x7FFFu);
                int idx = lane * 16 + j;
                k[j] = (idx < 1000) ? ((m << 16) | (unsigned)idx) : 0u;
            }
        }
        #pragma unroll
        for (int sz = 2; sz <= 16; sz <<= 1)
            #pragma unroll
            for (int st = sz >> 1; st >= 1; st >>= 1)
                #pragma unroll
                for (int ii = 0; ii < 16; ++ii) {
                    int j = ii ^ st;
                    if (j > ii) {
                        bool desc = ((ii & sz) == 0);
                        unsigned lo = k[ii], hi = k[j];
                        unsigned mx = lo > hi ? lo : hi;
                        unsigned mn = lo > hi ? hi : lo;
                        k[ii] = desc ? mx : mn;
                        k[j] = desc ? mn : mx;
                    }
                }
        unsigned mine = 0;
        #pragma unroll
        for (int r = 0; r < 12; ++r) {
            unsigned m = k[0];
            m = dppmax<0xB1>(m);
            m = dppmax<0x4E>(m);
            m = dppmax<0x141>(m);
            m = dppmax<0x140>(m);
            m = dppmax<0x142>(m);
            m = dppmax<0x143>(m);
            unsigned wm = (unsigned)__builtin_amdgcn_readlane((int)m, 63);
            if (lane == r) mine = wm;
            if (k[0] == wm) {
                #pragma unroll
                for (int s = 0; s < 12; ++s) k[s] = k[s + 1];
            }
        }
        if (lane < 12) top[(size_t)(qb + ql) * NC + lane] = (int)(mine & 0xFFFFu);
    }
}

// -------------------------------------------------------------- refine ------
// Also emits featbf (bf16 copy of feat) so k_mlp can consume A-fragments
// straight from global with no LDS staging / no per-chunk barriers.
__global__ __launch_bounds__(256) void k_refine(const float* __restrict__ feat,
        const float* __restrict__ bank, const int* __restrict__ top,
        const double* __restrict__ binv, short* __restrict__ nf,
        short* __restrict__ featbf)
{
    __shared__ int    cidxL[16 * NC];
    __shared__ float  bdF[16 * NC];
    __shared__ double bdD[16 * NC];
    __shared__ float  simsF[16 * NC];
    __shared__ double simsD[16 * NC];
    __shared__ float  qiL[16];
    __shared__ int    flagL[16];
    __shared__ int    selidx[16][5];
    __shared__ float  selw[16][5];

    const int t = threadIdx.x, lane = t & 63, w = t >> 6;
    const int g = lane >> 4, u = lane & 15;
    const int ql = w * 4 + g;
    const int qbase = blockIdx.x * 16;
    const int q = qbase + ql;

    if (t < 16 * NC) {
        const int c = top[(size_t)qbase * NC + t];
        cidxL[t] = c;
        const double b = binv[c];
        bdD[t] = b; bdF[t] = (float)b;
    }
    __syncthreads();

    int ci[NC];
    #pragma unroll
    for (int c = 0; c < NC; ++c) ci[c] = cidxL[ql * NC + c];

    float qf[16];
    float ssf = 0.f;
    #pragma unroll
    for (int j = 0; j < 4; ++j) {
        float4 v = *(const float4*)(feat + (size_t)q * DIM + j * 64 + u * 4);
        qf[j*4+0] = v.x; qf[j*4+1] = v.y; qf[j*4+2] = v.z; qf[j*4+3] = v.w;
        ssf += v.x*v.x + v.y*v.y + v.z*v.z + v.w*v.w;
    }
    // emit bf16 feat copy (same f32bf rounding k_mlp used to apply inline)
    {
        short* fb = featbf + (size_t)q * DIM + u * 4;
        #pragma unroll
        for (int j = 0; j < 4; ++j) {
            uint2 pk;
            pk.x = ((unsigned)(unsigned short)f32bf(qf[j*4+0])) |
                   (((unsigned)(unsigned short)f32bf(qf[j*4+1])) << 16);
            pk.y = ((unsigned)(unsigned short)f32bf(qf[j*4+2])) |
                   (((unsigned)(unsigned short)f32bf(qf[j*4+3])) << 16);
            *(uint2*)(fb + j * 64) = pk;
        }
    }
    #pragma unroll
    for (int o = 1; o < 16; o <<= 1) ssf += __shfl_xor(ssf, o, 16);
    float nq = sqrtf(ssf); if (nq < 1e-12f) nq = 1e-12f;
    if (u == 0) qiL[ql] = 1.f / nq;

    float s[NC];
    #pragma unroll
    for (int c = 0; c < NC; ++c) {
        const float* brow = bank + (size_t)ci[c] * DIM + u * 4;
        float a0 = 0.f, a1 = 0.f, a2 = 0.f, a3 = 0.f;
        #pragma unroll
        for (int j = 0; j < 4; ++j) {
            float4 b = *(const float4*)(brow + j * 64);
            a0 += qf[j*4+0] * b.x; a1 += qf[j*4+1] * b.y;
            a2 += qf[j*4+2] * b.z; a3 += qf[j*4+3] * b.w;
        }
        s[c] = (a0 + a1) + (a2 + a3);
    }
    #pragma unroll
    for (int o = 1; o < 16; o <<= 1)
        #pragma unroll
        for (int c = 0; c < NC; ++c) s[c] += __shfl_xor(s[c], o, 16);
    #pragma unroll
    for (int c = 0; c < NC; ++c) if (u == c) simsF[ql * NC + c] = s[c];
    __syncthreads();

    if (t < 16) {
        const float qi2 = qiL[t];
        float vf[NC];
        unsigned long long key[NC];
        int cid[NC];
        #pragma unroll
        for (int c = 0; c < NC; ++c) {
            cid[c] = cidxL[t * NC + c];
            float v = simsF[t * NC + c] * qi2 * bdF[t * NC + c];
            vf[c] = v;
            unsigned ub = __builtin_bit_cast(unsigned, v);
            unsigned m = (ub >> 31) ? ~ub : (ub | 0x80000000u);
            key[c] = ((unsigned long long)m << 10) | (unsigned long long)(1023 - cid[c]);
        }
        int rank[NC];
        #pragma unroll
        for (int c = 0; c < NC; ++c) rank[c] = 0;
        #pragma unroll
        for (int c1 = 0; c1 < NC; ++c1)
            #pragma unroll
            for (int c2 = c1 + 1; c2 < NC; ++c2) {
                const bool gt = key[c1] > key[c2];
                rank[c2] += gt ? 1 : 0;
                rank[c1] += gt ? 0 : 1;
            }
        float v5 = 0.f, v6 = 0.f;
        #pragma unroll
        for (int c = 0; c < NC; ++c) {
            v5 += (rank[c] == 4) ? vf[c] : 0.f;
            v6 += (rank[c] == 5) ? vf[c] : 0.f;
        }
        flagL[t] = (v5 - v6) < 2e-6f;

        float vm = vf[0];
        #pragma unroll
        for (int c = 1; c < NC; ++c) vm = fmaxf(vm, vf[c]);
        float e[NC]; float wsum = 0.f;
        #pragma unroll
        for (int c = 0; c < NC; ++c) {
            float ex = __expf(vf[c] - vm);
            ex = (rank[c] < 5) ? ex : 0.f;
            e[c] = ex; wsum += ex;
        }
        const float inv = 1.f / wsum;
        #pragma unroll
        for (int k = 0; k < 5; ++k) {
            int idx = 0; float wv = 0.f;
            #pragma unroll
            for (int c = 0; c < NC; ++c) {
                const bool is = (rank[c] == k);
                idx += is ? cid[c] : 0;
                wv  += is ? e[c]  : 0.f;
            }
            selidx[t][k] = idx; selw[t][k] = wv * inv;
        }
    }
    __syncthreads();

    if (flagL[ql]) {
        double ssd = 0.0;
        #pragma unroll
        for (int j = 0; j < 16; ++j) ssd += (double)qf[j] * (double)qf[j];
        #pragma unroll
        for (int o = 1; o < 16; o <<= 1) ssd += __shfl_xor(ssd, o, 16);
        double nd = sqrt(ssd); if (nd < 1e-12) nd = 1e-12;
        const double qid = 1.0 / nd;
        double sd[NC];
        #pragma unroll
        for (int c = 0; c < NC; ++c) {
            const float* brow = bank + (size_t)ci[c] * DIM + u * 4;
            double a0 = 0, a1 = 0, a2 = 0, a3 = 0;
            #pragma unroll
            for (int j = 0; j < 4; ++j) {
                float4 b = *(const float4*)(brow + j * 64);
                a0 += (double)qf[j*4+0] * b.x; a1 += (double)qf[j*4+1] * b.y;
                a2 += (double)qf[j*4+2] * b.z; a3 += (double)qf[j*4+3] * b.w;
            }
            sd[c] = (a0 + a1) + (a2 + a3);
        }
        #pragma unroll
        for (int o = 1; o < 16; o <<= 1)
            #pragma unroll
            for (int c = 0; c < NC; ++c) sd[c] += __shfl_xor(sd[c], o, 16);
        #pragma unroll
        for (int c = 0; c < NC; ++c)
            if (u == c) simsD[ql * NC + c] = sd[c] * qid * bdD[ql * NC + c];
    }
    __syncthreads();

    if (t < 16 && flagL[t]) {
        double vd[NC];
        unsigned long long key[NC];
        int cid[NC];
        #pragma unroll
        for (int c = 0; c < NC; ++c) {
            cid[c] = cidxL[t * NC + c];
            double v = simsD[t * NC + c];
            vd[c] = v;
            unsigned long long ub = __builtin_bit_cast(unsigned long long, v);
            unsigned long long m = (ub >> 63) ? ~ub : (ub | 0x8000000000000000ULL);
            key[c] = (m & ~0x3FFULL) | (unsigned long long)(1023 - cid[c]);
        }
        int rank[NC];
        #pragma unroll
        for (int c = 0; c < NC; ++c) rank[c] = 0;
        #pragma unroll
        for (int c1 = 0; c1 < NC; ++c1)
            #pragma unroll
            for (int c2 = c1 + 1; c2 < NC; ++c2) {
                const bool gt = key[c1] > key[c2];
                rank[c2] += gt ? 1 : 0;
                rank[c1] += gt ? 0 : 1;
            }
        float vf[NC];
        #pragma unroll
        for (int c = 0; c < NC; ++c) vf[c] = (float)vd[c];
        float vm = vf[0];
        #pragma unroll
        for (int c = 1; c < NC; ++c) vm = fmaxf(vm, vf[c]);
        float e[NC]; float wsum = 0.f;
        #pragma unroll
        for (int c = 0; c < NC; ++c) {
            float ex = __expf(vf[c] - vm);
            ex = (rank[c] < 5) ? ex : 0.f;
            e[c] = ex; wsum += ex;
        }
        const float inv = 1.f / wsum;
        #pragma unroll
        for (int k = 0; k < 5; ++k) {
            int idx = 0; float wv = 0.f;
            #pragma unroll
            for (int c = 0; c < NC; ++c) {
                const bool is = (rank[c] == k);
                idx += is ? cid[c] : 0;
                wv  += is ? e[c]  : 0.f;
            }
            selidx[t][k] = idx; selw[t][k] = wv * inv;
        }
    }
    __syncthreads();

    float wk[5]; int ik[5];
    #pragma unroll
    for (int k = 0; k < 5; ++k) { wk[k] = selw[ql][k]; ik[k] = selidx[ql][k]; }
    float4 oa[4];
    #pragma unroll
    for (int j = 0; j < 4; ++j) { oa[j].x = 0.f; oa[j].y = 0.f; oa[j].z = 0.f; oa[j].w = 0.f; }
    #pragma unroll
    for (int k = 0; k < 5; ++k) {
        const float wc = wk[k];
        const float* brow = bank + (size_t)ik[k] * DIM + u * 4;
        #pragma unroll
        for (int j = 0; j < 4; ++j) {
            float4 b = *(const float4*)(brow + j * 64);
            oa[j].x += wc * b.x; oa[j].y += wc * b.y;
            oa[j].z += wc * b.z; oa[j].w += wc * b.w;
        }
    }
    short* od = nf + (size_t)q * DIM + u * 4;
    #pragma unroll
    for (int j = 0; j < 4; ++j) {
        uint2 pk;
        pk.x = ((unsigned)(unsigned short)f32bf(oa[j].x)) |
               (((unsigned)(unsigned short)f32bf(oa[j].y)) << 16);
        pk.y = ((unsigned)(unsigned short)f32bf(oa[j].z)) |
               (((unsigned)(unsigned short)f32bf(oa[j].w)) << 16);
        *(uint2*)(od + j * 64) = pk;
    }
}

// ---------------------------------------------------------- fused MLP v3 ----
// (64-row tile, 64 VGPR + 64 AGPR, 4 blocks/CU, 86us measured. ILP > TLP.)
__global__ __launch_bounds__(256, 4) void k_mlp(const short* __restrict__ featbf,
        const short* __restrict__ nf, const short* __restrict__ w1bf,
        const short* __restrict__ w2bf, const float* __restrict__ b1,
        const float* __restrict__ b2, float* __restrict__ out)
{
    __shared__ alignas(16) short Hs[64 * 264];
    const int t = threadIdx.x, lane = t & 63, w = t >> 6;
    const int mb = blockIdx.x * 64;
    const int n16 = lane & 15, ko = (lane >> 4) << 3;
    const int rq = (lane >> 4) << 2, cc = lane & 15;
    const f32x4 vzero = {0.f, 0.f, 0.f, 0.f};

    f32x4 acc[4][4];
    #pragma unroll
    for (int a = 0; a < 4; ++a)
        #pragma unroll
        for (int b = 0; b < 4; ++b) acc[a][b] = vzero;

    const short* A0 = featbf + (size_t)mb * 256 + ko;
    const short* A1 = nf     + (size_t)mb * 256 + ko;
    const short* Wp = w1bf + (size_t)(w * 64 + n16) * 512 + ko;

    // ---- layer 1, K-chunks 0..7: A = featbf ----
    #pragma unroll
    for (int kc = 0; kc < 8; ++kc) {
        short8 af[4], bf[4];
        #pragma unroll
        for (int mt = 0; mt < 4; ++mt)
            af[mt] = *(const short8*)(A0 + (mt * 16 + n16) * 256 + kc * 32);
        #pragma unroll
        for (int nt = 0; nt < 4; ++nt)
            bf[nt] = *(const short8*)(Wp + (size_t)nt * 16 * 512 + kc * 32);
        #pragma unroll
        for (int mt = 0; mt < 4; ++mt)
            #pragma unroll
            for (int nt = 0; nt < 4; ++nt)
                acc[mt][nt] = __builtin_amdgcn_mfma_f32_16x16x32_bf16(af[mt], bf[nt], acc[mt][nt], 0, 0, 0);
    }
    // ---- layer 1, K-chunks 8..15: A = nf ----
    #pragma unroll
    for (int kc = 0; kc < 8; ++kc) {
        short8 af[4], bf[4];
        #pragma unroll
        for (int mt = 0; mt < 4; ++mt)
            af[mt] = *(const short8*)(A1 + (mt * 16 + n16) * 256 + kc * 32);
        #pragma unroll
        for (int nt = 0; nt < 4; ++nt)
            bf[nt] = *(const short8*)(Wp + (size_t)nt * 16 * 512 + (kc + 8) * 32);
        #pragma unroll
        for (int mt = 0; mt < 4; ++mt)
            #pragma unroll
            for (int nt = 0; nt < 4; ++nt)
                acc[mt][nt] = __builtin_amdgcn_mfma_f32_16x16x32_bf16(af[mt], bf[nt], acc[mt][nt], 0, 0, 0);
    }

    // epilogue 1: bias + relu -> Hs
    #pragma unroll
    for (int mt = 0; mt < 4; ++mt)
        #pragma unroll
        for (int nt = 0; nt < 4; ++nt) {
            const int row = mt * 16 + rq;
            const int col = w * 64 + nt * 16 + cc;
            const float bias = b1[col];
            #pragma unroll
            for (int rr = 0; rr < 4; ++rr) {
                float v = acc[mt][nt][rr] + bias;
                Hs[(row + rr) * 264 + col] = f32bf(fmaxf(v, 0.f));
            }
        }
    #pragma unroll
    for (int a = 0; a < 4; ++a)
        #pragma unroll
        for (int b = 0; b < 4; ++b) acc[a][b] = vzero;
    __syncthreads();

    // ---- layer 2: barrier-free K-loop (Hs read-only, weights global) ----
    #pragma unroll
    for (int kc = 0; kc < 8; ++kc) {
        short8 bf[4];
        #pragma unroll
        for (int nt = 0; nt < 4; ++nt)
            bf[nt] = *(const short8*)(w2bf + (size_t)(w * 64 + nt * 16 + n16) * 256 + kc * 32 + ko);
        short8 af[4];
        #pragma unroll
        for (int mt = 0; mt < 4; ++mt)
            af[mt] = *(const short8*)(Hs + (mt * 16 + n16) * 264 + kc * 32 + ko);
        #pragma unroll
        for (int mt = 0; mt < 4; ++mt)
            #pragma unroll
            for (int nt = 0; nt < 4; ++nt)
                acc[mt][nt] = __builtin_amdgcn_mfma_f32_16x16x32_bf16(af[mt], bf[nt], acc[mt][nt], 0, 0, 0);
    }
    #pragma unroll
    for (int mt = 0; mt < 4; ++mt)
        #pragma unroll
        for (int nt = 0; nt < 4; ++nt) {
            const int row = mb + mt * 16 + rq;
            const int col = w * 64 + nt * 16 + cc;
            const float bias = b2[col];
            #pragma unroll
            for (int rr = 0; rr < 4; ++rr)
                out[(size_t)(row + rr) * 256 + col] = acc[mt][nt][rr] + bias;
        }
}

// ------------------------------------------------------------- launcher -----
extern "C" void kernel_launch(void* const* d_in, const int* in_sizes, int n_in,
                              void* d_out, int out_size, void* d_ws, size_t ws_size,
                              hipStream_t stream) {
    const float* feat = (const float*)d_in[0];
    const float* bank = (const float*)d_in[1];
    const float* W1   = (const float*)d_in[2];
    const float* b1   = (const float*)d_in[3];
    const float* W2   = (const float*)d_in[4];
    const float* b2   = (const float*)d_in[5];
    float* out = (float*)d_out;

    char* ws = (char*)d_ws;
    short*  bnbf = (short*)(ws + 0);              // 1024*256*2   = 524288
    double* binv = (double*)(ws + 524288);        // 1024*8       = 8192
    short*  w1bf = (short*)(ws + 532480);         // 131072*2     = 262144
    short*  w2bf = (short*)(ws + 794624);         // 65536*2      = 131072
    int*    top  = (int*)(ws + 925696);           // 65536*12*4   = 3145728
    short*  nf   = (short*)(ws + 4071424);        // 65536*256*2  = 33554432
    short*  featbf = (short*)(ws + 37625856);     // 65536*256*2  = 33554432
    // total 71180288 bytes (sims live in LDS; no global X buffer)

    k_prep<<<1792, 256, 0, stream>>>(bank, W1, W2, bnbf, binv, w1bf, w2bf);
    k_sims<<<2048, 512, 0, stream>>>(feat, bnbf, top);
    k_refine<<<4096, 256, 0, stream>>>(feat, bank, top, binv, nf, featbf);
    k_mlp  <<<1024, 256, 0, stream>>>(featbf, nf, w1bf, w2bf, b1, b2, out);
}

// Round 6
// 391.584 us; speedup vs baseline: 1.1915x; 1.1915x over previous
//
#include <hip/hip_runtime.h>

#define DIM 256
#define NC 12

typedef __attribute__((ext_vector_type(8))) short short8;
typedef __attribute__((ext_vector_type(4))) float f32x4;

__device__ __forceinline__ short f32bf(float f) {
    unsigned u = __builtin_bit_cast(unsigned, f);
    unsigned r = u + 0x7FFFu + ((u >> 16) & 1u);
    return (short)(r >> 16);
}

template<int CTRL>
__device__ __forceinline__ unsigned dppmax(unsigned x) {
    unsigned y = (unsigned)__builtin_amdgcn_update_dpp(0, (int)x, CTRL, 0xF, 0xF, true);
    return x > y ? x : y;
}

// ---------------------------------------------------------------- prep ------
__global__ __launch_bounds__(256) void k_prep(const float* __restrict__ bank,
        const float* __restrict__ W1, const float* __restrict__ W2,
        short* __restrict__ bnbf, double* __restrict__ binv,
        short* __restrict__ w1bf, short* __restrict__ w2bf)
{
    __shared__ double part[4];
    __shared__ double s_inv;
    const int bid = blockIdx.x, t = threadIdx.x;
    if (bid < 1024) {
        const int row = bid;
        if (row < 1000) {
            float v = bank[(size_t)row * DIM + t];
            double ssq = (double)v * (double)v;
            for (int o = 32; o > 0; o >>= 1) ssq += __shfl_down(ssq, o);
            if ((t & 63) == 0) part[t >> 6] = ssq;
            __syncthreads();
            if (t == 0) {
                double s = part[0] + part[1] + part[2] + part[3];
                double n = sqrt(s); if (n < 1e-12) n = 1e-12;
                double inv = 1.0 / n;
                binv[row] = inv; s_inv = inv;
            }
            __syncthreads();
            bnbf[(size_t)row * DIM + t] = f32bf((float)((double)v * s_inv));
        } else {
            bnbf[(size_t)row * DIM + t] = 0;
            if (t == 0) binv[row] = 0.0;
        }
    } else if (bid < 1536) {
        const int i = (bid - 1024) * 256 + t;
        w1bf[i] = f32bf(W1[i]);
    } else {
        const int i = (bid - 1536) * 256 + t;
        w2bf[i] = f32bf(W2[i]);
    }
}

// ------------------------------------------------- sims + select (v4) -------
// r4 structure (256 thr, 32 q/block, 66 KB S-tile in LDS, 2 blocks/CU) but
// with an explicit 2-deep prefetch register ring (3 slots, statically
// indexed under full unroll) so the ~300-cyc L2 latency of the bank-row
// loads hides under two chunks' worth of MFMA+store work. r5's 512-thread
// variant regressed (1 block/CU, phase convoy) - reverted.
__global__ __launch_bounds__(256) void k_sims(const float* __restrict__ feat,
        const short* __restrict__ bnbf, int* __restrict__ top)
{
    __shared__ alignas(16) short S[32 * 1032];
    const int t = threadIdx.x, lane = t & 63, w = t >> 6;   // w = 0..3
    const int n16 = lane & 15, q4 = lane >> 4;
    const int qb = blockIdx.x * 32;

    // Q fragments: lane reads feat[qb + nt*16 + n16][kc*32 + q4*8 .. +8]
    short8 bq[8][2];
    #pragma unroll
    for (int kc = 0; kc < 8; ++kc)
        #pragma unroll
        for (int nt = 0; nt < 2; ++nt) {
            const float4* s = (const float4*)(feat + (size_t)(qb + nt * 16 + n16) * DIM + kc * 32 + q4 * 8);
            float4 v0 = s[0], v1 = s[1];
            short8 f;
            f[0] = f32bf(v0.x); f[1] = f32bf(v0.y); f[2] = f32bf(v0.z); f[3] = f32bf(v0.w);
            f[4] = f32bf(v1.x); f[5] = f32bf(v1.y); f[6] = f32bf(v1.z); f[7] = f32bf(v1.w);
            bq[kc][nt] = f;
        }

    // A base: bank row (w*16 + n16), column q4*8; chunk = 64 rows = 32768 B
    const char* Abase = (const char*)bnbf + ((size_t)(w * 16 + n16) * DIM + q4 * 8) * 2;
    const f32x4 vzero = {0.f, 0.f, 0.f, 0.f};

    // 3-slot register ring, 2-deep prefetch. All indices compile-time
    // (full unroll) -> registers, not scratch.
    short8 A[3][8];
    #pragma unroll
    for (int kc = 0; kc < 8; ++kc) A[0][kc] = *(const short8*)(Abase + kc * 64);
    #pragma unroll
    for (int kc = 0; kc < 8; ++kc) A[1][kc] = *(const short8*)(Abase + 32768 + kc * 64);

    #pragma unroll
    for (int chunk = 0; chunk < 16; ++chunk) {
        if (chunk + 2 < 16) {
            const char* nb = Abase + (size_t)(chunk + 2) * 32768;
            #pragma unroll
            for (int kc = 0; kc < 8; ++kc)
                A[(chunk + 2) % 3][kc] = *(const short8*)(nb + kc * 64);
        }
        f32x4 acc0 = vzero, acc1 = vzero;
        #pragma unroll
        for (int kc = 0; kc < 8; ++kc) {
            acc0 = __builtin_amdgcn_mfma_f32_16x16x32_bf16(A[chunk % 3][kc], bq[kc][0], acc0, 0, 0, 0);
            acc1 = __builtin_amdgcn_mfma_f32_16x16x32_bf16(A[chunk % 3][kc], bq[kc][1], acc1, 0, 0, 0);
        }
        const int bankb = chunk * 64 + w * 16 + q4 * 4;
        {
            uint2 u;
            u.x = ((unsigned)(unsigned short)f32bf(acc0[0])) |
                  (((unsigned)(unsigned short)f32bf(acc0[1])) << 16);
            u.y = ((unsigned)(unsigned short)f32bf(acc0[2])) |
                  (((unsigned)(unsigned short)f32bf(acc0[3])) << 16);
            *(uint2*)(S + (size_t)n16 * 1032 + bankb) = u;
            u.x = ((unsigned)(unsigned short)f32bf(acc1[0])) |
                  (((unsigned)(unsigned short)f32bf(acc1[1])) << 16);
            u.y = ((unsigned)(unsigned short)f32bf(acc1[2])) |
                  (((unsigned)(unsigned short)f32bf(acc1[3])) << 16);
            *(uint2*)(S + (size_t)(16 + n16) * 1032 + bankb) = u;
        }
    }
    __syncthreads();

    // ---- fused select: 4 waves x 8 queries each, reads from LDS ----
    for (int i = 0; i < 8; ++i) {
        const int ql = w * 8 + i;
        const uint4* p = (const uint4*)(S + (size_t)ql * 1032 + lane * 16);
        uint4 a = p[0], b = p[1];

        unsigned k[16];
        {
            unsigned words[8] = {a.x, a.y, a.z, a.w, b.x, b.y, b.z, b.w};
            #pragma unroll
            for (int j = 0; j < 16; ++j) {
                unsigned h = (j & 1) ? (words[j >> 1] >> 16) : (words[j >> 1] & 0xFFFFu);
                unsigned m = (h ^ 0x8000u) ^ ((0u - (h >> 15)) & 0x7FFFu);
                int idx = lane * 16 + j;
                k[j] = (idx < 1000) ? ((m << 16) | (unsigned)idx) : 0u;
            }
        }
        #pragma unroll
        for (int sz = 2; sz <= 16; sz <<= 1)
            #pragma unroll
            for (int st = sz >> 1; st >= 1; st >>= 1)
                #pragma unroll
                for (int ii = 0; ii < 16; ++ii) {
                    int j = ii ^ st;
                    if (j > ii) {
                        bool desc = ((ii & sz) == 0);
                        unsigned lo = k[ii], hi = k[j];
                        unsigned mx = lo > hi ? lo : hi;
                        unsigned mn = lo > hi ? hi : lo;
                        k[ii] = desc ? mx : mn;
                        k[j] = desc ? mn : mx;
                    }
                }
        unsigned mine = 0;
        #pragma unroll
        for (int r = 0; r < 12; ++r) {
            unsigned m = k[0];
            m = dppmax<0xB1>(m);
            m = dppmax<0x4E>(m);
            m = dppmax<0x141>(m);
            m = dppmax<0x140>(m);
            m = dppmax<0x142>(m);
            m = dppmax<0x143>(m);
            unsigned wm = (unsigned)__builtin_amdgcn_readlane((int)m, 63);
            if (lane == r) mine = wm;
            if (k[0] == wm) {
                #pragma unroll
                for (int s = 0; s < 12; ++s) k[s] = k[s + 1];
            }
        }
        if (lane < 12) top[(size_t)(qb + ql) * NC + lane] = (int)(mine & 0xFFFFu);
    }
}

// -------------------------------------------------------------- refine ------
// Also emits featbf (bf16 copy of feat) so k_mlp can consume A-fragments
// straight from global with no LDS staging / no per-chunk barriers.
__global__ __launch_bounds__(256) void k_refine(const float* __restrict__ feat,
        const float* __restrict__ bank, const int* __restrict__ top,
        const double* __restrict__ binv, short* __restrict__ nf,
        short* __restrict__ featbf)
{
    __shared__ int    cidxL[16 * NC];
    __shared__ float  bdF[16 * NC];
    __shared__ double bdD[16 * NC];
    __shared__ float  simsF[16 * NC];
    __shared__ double simsD[16 * NC];
    __shared__ float  qiL[16];
    __shared__ int    flagL[16];
    __shared__ int    selidx[16][5];
    __shared__ float  selw[16][5];

    const int t = threadIdx.x, lane = t & 63, w = t >> 6;
    const int g = lane >> 4, u = lane & 15;
    const int ql = w * 4 + g;
    const int qbase = blockIdx.x * 16;
    const int q = qbase + ql;

    if (t < 16 * NC) {
        const int c = top[(size_t)qbase * NC + t];
        cidxL[t] = c;
        const double b = binv[c];
        bdD[t] = b; bdF[t] = (float)b;
    }
    __syncthreads();

    int ci[NC];
    #pragma unroll
    for (int c = 0; c < NC; ++c) ci[c] = cidxL[ql * NC + c];

    float qf[16];
    float ssf = 0.f;
    #pragma unroll
    for (int j = 0; j < 4; ++j) {
        float4 v = *(const float4*)(feat + (size_t)q * DIM + j * 64 + u * 4);
        qf[j*4+0] = v.x; qf[j*4+1] = v.y; qf[j*4+2] = v.z; qf[j*4+3] = v.w;
        ssf += v.x*v.x + v.y*v.y + v.z*v.z + v.w*v.w;
    }
    // emit bf16 feat copy (same f32bf rounding k_mlp used to apply inline)
    {
        short* fb = featbf + (size_t)q * DIM + u * 4;
        #pragma unroll
        for (int j = 0; j < 4; ++j) {
            uint2 pk;
            pk.x = ((unsigned)(unsigned short)f32bf(qf[j*4+0])) |
                   (((unsigned)(unsigned short)f32bf(qf[j*4+1])) << 16);
            pk.y = ((unsigned)(unsigned short)f32bf(qf[j*4+2])) |
                   (((unsigned)(unsigned short)f32bf(qf[j*4+3])) << 16);
            *(uint2*)(fb + j * 64) = pk;
        }
    }
    #pragma unroll
    for (int o = 1; o < 16; o <<= 1) ssf += __shfl_xor(ssf, o, 16);
    float nq = sqrtf(ssf); if (nq < 1e-12f) nq = 1e-12f;
    if (u == 0) qiL[ql] = 1.f / nq;

    float s[NC];
    #pragma unroll
    for (int c = 0; c < NC; ++c) {
        const float* brow = bank + (size_t)ci[c] * DIM + u * 4;
        float a0 = 0.f, a1 = 0.f, a2 = 0.f, a3 = 0.f;
        #pragma unroll
        for (int j = 0; j < 4; ++j) {
            float4 b = *(const float4*)(brow + j * 64);
            a0 += qf[j*4+0] * b.x; a1 += qf[j*4+1] * b.y;
            a2 += qf[j*4+2] * b.z; a3 += qf[j*4+3] * b.w;
        }
        s[c] = (a0 + a1) + (a2 + a3);
    }
    #pragma unroll
    for (int o = 1; o < 16; o <<= 1)
        #pragma unroll
        for (int c = 0; c < NC; ++c) s[c] += __shfl_xor(s[c], o, 16);
    #pragma unroll
    for (int c = 0; c < NC; ++c) if (u == c) simsF[ql * NC + c] = s[c];
    __syncthreads();

    if (t < 16) {
        const float qi2 = qiL[t];
        float vf[NC];
        unsigned long long key[NC];
        int cid[NC];
        #pragma unroll
        for (int c = 0; c < NC; ++c) {
            cid[c] = cidxL[t * NC + c];
            float v = simsF[t * NC + c] * qi2 * bdF[t * NC + c];
            vf[c] = v;
            unsigned ub = __builtin_bit_cast(unsigned, v);
            unsigned m = (ub >> 31) ? ~ub : (ub | 0x80000000u);
            key[c] = ((unsigned long long)m << 10) | (unsigned long long)(1023 - cid[c]);
        }
        int rank[NC];
        #pragma unroll
        for (int c = 0; c < NC; ++c) rank[c] = 0;
        #pragma unroll
        for (int c1 = 0; c1 < NC; ++c1)
            #pragma unroll
            for (int c2 = c1 + 1; c2 < NC; ++c2) {
                const bool gt = key[c1] > key[c2];
                rank[c2] += gt ? 1 : 0;
                rank[c1] += gt ? 0 : 1;
            }
        float v5 = 0.f, v6 = 0.f;
        #pragma unroll
        for (int c = 0; c < NC; ++c) {
            v5 += (rank[c] == 4) ? vf[c] : 0.f;
            v6 += (rank[c] == 5) ? vf[c] : 0.f;
        }
        flagL[t] = (v5 - v6) < 2e-6f;

        float vm = vf[0];
        #pragma unroll
        for (int c = 1; c < NC; ++c) vm = fmaxf(vm, vf[c]);
        float e[NC]; float wsum = 0.f;
        #pragma unroll
        for (int c = 0; c < NC; ++c) {
            float ex = __expf(vf[c] - vm);
            ex = (rank[c] < 5) ? ex : 0.f;
            e[c] = ex; wsum += ex;
        }
        const float inv = 1.f / wsum;
        #pragma unroll
        for (int k = 0; k < 5; ++k) {
            int idx = 0; float wv = 0.f;
            #pragma unroll
            for (int c = 0; c < NC; ++c) {
                const bool is = (rank[c] == k);
                idx += is ? cid[c] : 0;
                wv  += is ? e[c]  : 0.f;
            }
            selidx[t][k] = idx; selw[t][k] = wv * inv;
        }
    }
    __syncthreads();

    if (flagL[ql]) {
        double ssd = 0.0;
        #pragma unroll
        for (int j = 0; j < 16; ++j) ssd += (double)qf[j] * (double)qf[j];
        #pragma unroll
        for (int o = 1; o < 16; o <<= 1) ssd += __shfl_xor(ssd, o, 16);
        double nd = sqrt(ssd); if (nd < 1e-12) nd = 1e-12;
        const double qid = 1.0 / nd;
        double sd[NC];
        #pragma unroll
        for (int c = 0; c < NC; ++c) {
            const float* brow = bank + (size_t)ci[c] * DIM + u * 4;
            double a0 = 0, a1 = 0, a2 = 0, a3 = 0;
            #pragma unroll
            for (int j = 0; j < 4; ++j) {
                float4 b = *(const float4*)(brow + j * 64);
                a0 += (double)qf[j*4+0] * b.x; a1 += (double)qf[j*4+1] * b.y;
                a2 += (double)qf[j*4+2] * b.z; a3 += (double)qf[j*4+3] * b.w;
            }
            sd[c] = (a0 + a1) + (a2 + a3);
        }
        #pragma unroll
        for (int o = 1; o < 16; o <<= 1)
            #pragma unroll
            for (int c = 0; c < NC; ++c) sd[c] += __shfl_xor(sd[c], o, 16);
        #pragma unroll
        for (int c = 0; c < NC; ++c)
            if (u == c) simsD[ql * NC + c] = sd[c] * qid * bdD[ql * NC + c];
    }
    __syncthreads();

    if (t < 16 && flagL[t]) {
        double vd[NC];
        unsigned long long key[NC];
        int cid[NC];
        #pragma unroll
        for (int c = 0; c < NC; ++c) {
            cid[c] = cidxL[t * NC + c];
            double v = simsD[t * NC + c];
            vd[c] = v;
            unsigned long long ub = __builtin_bit_cast(unsigned long long, v);
            unsigned long long m = (ub >> 63) ? ~ub : (ub | 0x8000000000000000ULL);
            key[c] = (m & ~0x3FFULL) | (unsigned long long)(1023 - cid[c]);
        }
        int rank[NC];
        #pragma unroll
        for (int c = 0; c < NC; ++c) rank[c] = 0;
        #pragma unroll
        for (int c1 = 0; c1 < NC; ++c1)
            #pragma unroll
            for (int c2 = c1 + 1; c2 < NC; ++c2) {
                const bool gt = key[c1] > key[c2];
                rank[c2] += gt ? 1 : 0;
                rank[c1] += gt ? 0 : 1;
            }
        float vf[NC];
        #pragma unroll
        for (int c = 0; c < NC; ++c) vf[c] = (float)vd[c];
        float vm = vf[0];
        #pragma unroll
        for (int c = 1; c < NC; ++c) vm = fmaxf(vm, vf[c]);
        float e[NC]; float wsum = 0.f;
        #pragma unroll
        for (int c = 0; c < NC; ++c) {
            float ex = __expf(vf[c] - vm);
            ex = (rank[c] < 5) ? ex : 0.f;
            e[c] = ex; wsum += ex;
        }
        const float inv = 1.f / wsum;
        #pragma unroll
        for (int k = 0; k < 5; ++k) {
            int idx = 0; float wv = 0.f;
            #pragma unroll
            for (int c = 0; c < NC; ++c) {
                const bool is = (rank[c] == k);
                idx += is ? cid[c] : 0;
                wv  += is ? e[c]  : 0.f;
            }
            selidx[t][k] = idx; selw[t][k] = wv * inv;
        }
    }
    __syncthreads();

    float wk[5]; int ik[5];
    #pragma unroll
    for (int k = 0; k < 5; ++k) { wk[k] = selw[ql][k]; ik[k] = selidx[ql][k]; }
    float4 oa[4];
    #pragma unroll
    for (int j = 0; j < 4; ++j) { oa[j].x = 0.f; oa[j].y = 0.f; oa[j].z = 0.f; oa[j].w = 0.f; }
    #pragma unroll
    for (int k = 0; k < 5; ++k) {
        const float wc = wk[k];
        const float* brow = bank + (size_t)ik[k] * DIM + u * 4;
        #pragma unroll
        for (int j = 0; j < 4; ++j) {
            float4 b = *(const float4*)(brow + j * 64);
            oa[j].x += wc * b.x; oa[j].y += wc * b.y;
            oa[j].z += wc * b.z; oa[j].w += wc * b.w;
        }
    }
    short* od = nf + (size_t)q * DIM + u * 4;
    #pragma unroll
    for (int j = 0; j < 4; ++j) {
        uint2 pk;
        pk.x = ((unsigned)(unsigned short)f32bf(oa[j].x)) |
               (((unsigned)(unsigned short)f32bf(oa[j].y)) << 16);
        pk.y = ((unsigned)(unsigned short)f32bf(oa[j].z)) |
               (((unsigned)(unsigned short)f32bf(oa[j].w)) << 16);
        *(uint2*)(od + j * 64) = pk;
    }
}

// ---------------------------------------------------------- fused MLP v3 ----
// (64-row tile, 64 VGPR + 64 AGPR, 4 blocks/CU, 86us measured. ILP > TLP.)
__global__ __launch_bounds__(256, 4) void k_mlp(const short* __restrict__ featbf,
        const short* __restrict__ nf, const short* __restrict__ w1bf,
        const short* __restrict__ w2bf, const float* __restrict__ b1,
        const float* __restrict__ b2, float* __restrict__ out)
{
    __shared__ alignas(16) short Hs[64 * 264];
    const int t = threadIdx.x, lane = t & 63, w = t >> 6;
    const int mb = blockIdx.x * 64;
    const int n16 = lane & 15, ko = (lane >> 4) << 3;
    const int rq = (lane >> 4) << 2, cc = lane & 15;
    const f32x4 vzero = {0.f, 0.f, 0.f, 0.f};

    f32x4 acc[4][4];
    #pragma unroll
    for (int a = 0; a < 4; ++a)
        #pragma unroll
        for (int b = 0; b < 4; ++b) acc[a][b] = vzero;

    const short* A0 = featbf + (size_t)mb * 256 + ko;
    const short* A1 = nf     + (size_t)mb * 256 + ko;
    const short* Wp = w1bf + (size_t)(w * 64 + n16) * 512 + ko;

    // ---- layer 1, K-chunks 0..7: A = featbf ----
    #pragma unroll
    for (int kc = 0; kc < 8; ++kc) {
        short8 af[4], bf[4];
        #pragma unroll
        for (int mt = 0; mt < 4; ++mt)
            af[mt] = *(const short8*)(A0 + (mt * 16 + n16) * 256 + kc * 32);
        #pragma unroll
        for (int nt = 0; nt < 4; ++nt)
            bf[nt] = *(const short8*)(Wp + (size_t)nt * 16 * 512 + kc * 32);
        #pragma unroll
        for (int mt = 0; mt < 4; ++mt)
            #pragma unroll
            for (int nt = 0; nt < 4; ++nt)
                acc[mt][nt] = __builtin_amdgcn_mfma_f32_16x16x32_bf16(af[mt], bf[nt], acc[mt][nt], 0, 0, 0);
    }
    // ---- layer 1, K-chunks 8..15: A = nf ----
    #pragma unroll
    for (int kc = 0; kc < 8; ++kc) {
        short8 af[4], bf[4];
        #pragma unroll
        for (int mt = 0; mt < 4; ++mt)
            af[mt] = *(const short8*)(A1 + (mt * 16 + n16) * 256 + kc * 32);
        #pragma unroll
        for (int nt = 0; nt < 4; ++nt)
            bf[nt] = *(const short8*)(Wp + (size_t)nt * 16 * 512 + (kc + 8) * 32);
        #pragma unroll
        for (int mt = 0; mt < 4; ++mt)
            #pragma unroll
            for (int nt = 0; nt < 4; ++nt)
                acc[mt][nt] = __builtin_amdgcn_mfma_f32_16x16x32_bf16(af[mt], bf[nt], acc[mt][nt], 0, 0, 0);
    }

    // epilogue 1: bias + relu -> Hs
    #pragma unroll
    for (int mt = 0; mt < 4; ++mt)
        #pragma unroll
        for (int nt = 0; nt < 4; ++nt) {
            const int row = mt * 16 + rq;
            const int col = w * 64 + nt * 16 + cc;
            const float bias = b1[col];
            #pragma unroll
            for (int rr = 0; rr < 4; ++rr) {
                float v = acc[mt][nt][rr] + bias;
                Hs[(row + rr) * 264 + col] = f32bf(fmaxf(v, 0.f));
            }
        }
    #pragma unroll
    for (int a = 0; a < 4; ++a)
        #pragma unroll
        for (int b = 0; b < 4; ++b) acc[a][b] = vzero;
    __syncthreads();

    // ---- layer 2: barrier-free K-loop (Hs read-only, weights global) ----
    #pragma unroll
    for (int kc = 0; kc < 8; ++kc) {
        short8 bf[4];
        #pragma unroll
        for (int nt = 0; nt < 4; ++nt)
            bf[nt] = *(const short8*)(w2bf + (size_t)(w * 64 + nt * 16 + n16) * 256 + kc * 32 + ko);
        short8 af[4];
        #pragma unroll
        for (int mt = 0; mt < 4; ++mt)
            af[mt] = *(const short8*)(Hs + (mt * 16 + n16) * 264 + kc * 32 + ko);
        #pragma unroll
        for (int mt = 0; mt < 4; ++mt)
            #pragma unroll
            for (int nt = 0; nt < 4; ++nt)
                acc[mt][nt] = __builtin_amdgcn_mfma_f32_16x16x32_bf16(af[mt], bf[nt], acc[mt][nt], 0, 0, 0);
    }
    #pragma unroll
    for (int mt = 0; mt < 4; ++mt)
        #pragma unroll
        for (int nt = 0; nt < 4; ++nt) {
            const int row = mb + mt * 16 + rq;
            const int col = w * 64 + nt * 16 + cc;
            const float bias = b2[col];
            #pragma unroll
            for (int rr = 0; rr < 4; ++rr)
                out[(size_t)(row + rr) * 256 + col] = acc[mt][nt][rr] + bias;
        }
}

// ------------------------------------------------------------- launcher -----
extern "C" void kernel_launch(void* const* d_in, const int* in_sizes, int n_in,
                              void* d_out, int out_size, void* d_ws, size_t ws_size,
                              hipStream_t stream) {
    const float* feat = (const float*)d_in[0];
    const float* bank = (const float*)d_in[1];
    const float* W1   = (const float*)d_in[2];
    const float* b1   = (const float*)d_in[3];
    const float* W2   = (const float*)d_in[4];
    const float* b2   = (const float*)d_in[5];
    float* out = (float*)d_out;

    char* ws = (char*)d_ws;
    short*  bnbf = (short*)(ws + 0);              // 1024*256*2   = 524288
    double* binv = (double*)(ws + 524288);        // 1024*8       = 8192
    short*  w1bf = (short*)(ws + 532480);         // 131072*2     = 262144
    short*  w2bf = (short*)(ws + 794624);         // 65536*2      = 131072
    int*    top  = (int*)(ws + 925696);           // 65536*12*4   = 3145728
    short*  nf   = (short*)(ws + 4071424);        // 65536*256*2  = 33554432
    short*  featbf = (short*)(ws + 37625856);     // 65536*256*2  = 33554432
    // total 71180288 bytes (sims live in LDS; no global X buffer)

    k_prep<<<1792, 256, 0, stream>>>(bank, W1, W2, bnbf, binv, w1bf, w2bf);
    k_sims<<<2048, 256, 0, stream>>>(feat, bnbf, top);
    k_refine<<<4096, 256, 0, stream>>>(feat, bank, top, binv, nf, featbf);
    k_mlp  <<<1024, 256, 0, stream>>>(featbf, nf, w1bf, w2bf, b1, b2, out);
}